// Round 3
// baseline (406.099 us; speedup 1.0000x reference)
//
#include <hip/hip_runtime.h>

// Fused truncated-scan linear RNN for MI355X (gfx950) — round 5.
//
// vs round 4: the 2x regression was register spill: conv24's win[27]
// (108 VGPRs) + head-path pressure in a 64-VGPR allocation pushed the
// sliding window into scratch, throttling resident waves chip-wide.
// Fixes: (a) 4-deep register RING for the window (static &3 indexing,
// 1 LDS b128/k instead of 4, no spill); (b) LDS 61440->56320 B (55
// slots; x_enc frags staged through the zero-slot region before window
// staging) -> back to 2 WG/CU; (c) make_tabs 33->25 steps (gamma_t =
// gamma_inf for t>=24), dead final updates skipped, conflict-free
// transpose reads.

#define TSEQ 512
#define NBAT 1024
#define NYD  32
#define NUD  32
#define NHD  128
#define MB   16    // batch rows per workgroup (one MFMA M-tile)
#define LCH  32    // rows per conv window
#define NCH  16    // chunk count (chunk 0 = head rows 0..32, 1..15 conv)
#define TENC 24    // encoder taps (truncated history)
#define KTAP 24    // decoder conv taps == truncation depth
#define RVS  132   // precompute LDS row stride (f32)

typedef __bf16 bf16x8 __attribute__((ext_vector_type(8)));
typedef __bf16 bf16x4 __attribute__((ext_vector_type(4)));
typedef float  f32x4  __attribute__((ext_vector_type(4)));

#define MFMA16(a, b, c) __builtin_amdgcn_mfma_f32_16x16x32_bf16((a), (b), (c), 0, 0, 0)

// workspace layout (bf16 element offsets)
#define WS_RK  0                       // [24][32][32]  R_k (value R_k[u][n] at [k][n][u])
#define WS_GY  (24 * 1024)             // [24][128][32] Gy_k^T (value Gy_k[y][h] at [k][h][y])
#define WS_GU  (WS_GY + 24 * 4096)     // [24][128][32] Gu_k^T
#define WS_EW  (WS_GU + 24 * 4096)     // [25][32][128] E_t^T  (value E_t[h][y] at [t][y][h])
#define WS_F32 (WS_EW + 25 * 4096)     // f32: gamma[34][32] (33=inf), beta[128]

__device__ __forceinline__ bf16x8 gather_w(const float* __restrict__ W, int ld,
                                           int k0, int col) {
  bf16x8 r;
#pragma unroll
  for (int j = 0; j < 8; ++j) r[j] = (__bf16)W[(k0 + j) * ld + col];
  return r;
}

__device__ __forceinline__ bf16x8 cvt8(float4 a, float4 b) {
  bf16x8 r;
  r[0] = (__bf16)a.x; r[1] = (__bf16)a.y; r[2] = (__bf16)a.z; r[3] = (__bf16)a.w;
  r[4] = (__bf16)b.x; r[5] = (__bf16)b.y; r[6] = (__bf16)b.z; r[7] = (__bf16)b.w;
  return r;
}

// 24-tap conv with 4-deep register ring window (no spill): per k, one
// fresh LDS b128 read; taps software-pipelined 2-deep from global (L2).
__device__ __forceinline__ void conv24ring(const __bf16* __restrict__ taps,
                                           const __bf16* __restrict__ ub,
                                           int l16, int qs, int lane,
                                           f32x4 acc[4][2]) {
#define TAPF(k, mt) (*(const bf16x8*)(taps + (k) * 1024 + ((mt) * 16 + l16) * 32 + qs))
#define WINF(i)     (*(const bf16x8*)(ub + (i) * 512 + lane * 8))
  bf16x8 w[4];
  w[23 & 3] = WINF(23);
  w[24 & 3] = WINF(24);
  w[25 & 3] = WINF(25);
  w[26 & 3] = WINF(26);
  bf16x8 t0a = TAPF(0, 0), t0b = TAPF(0, 1);
  bf16x8 t1a = TAPF(1, 0), t1b = TAPF(1, 1);
#pragma unroll
  for (int k = 0; k < KTAP; ++k) {
    bf16x8 t2a, t2b, wn;
    if (k + 2 < KTAP) { t2a = TAPF(k + 2, 0); t2b = TAPF(k + 2, 1); }
    if (k + 1 < KTAP) wn = WINF(22 - k);   // frag needed from iter k+1 on
#pragma unroll
    for (int r = 0; r < 4; ++r) {
      acc[r][0] = MFMA16(t0a, w[(23 - k + r) & 3], acc[r][0]);
      acc[r][1] = MFMA16(t0b, w[(23 - k + r) & 3], acc[r][1]);
    }
    if (k + 1 < KTAP) w[(22 - k) & 3] = wn;  // overwrites slot of (26-k)
    t0a = t1a; t0b = t1b;
    if (k + 2 < KTAP) { t1a = t2a; t1b = t2b; }
  }
#undef TAPF
#undef WINF
}

// ============ precompute: 4 parallel WGs, one per serial chain ============
__global__ __launch_bounds__(256) void make_tabs(
    const float* __restrict__ W_enc, const float* __restrict__ b_enc,
    const float* __restrict__ W_dec, const float* __restrict__ b_dec,
    const float* __restrict__ W_out, const float* __restrict__ b_out,
    __bf16* __restrict__ ws) {
  __shared__ __align__(16) float rv[2][48 * RVS];
  const int tid = threadIdx.x;
  const int wave = tid >> 6, lane = tid & 63;
  const int q = lane >> 4, l16 = lane & 15, qs = q * 8;
  const int role = blockIdx.x;
  float* Fz = (float*)(ws + WS_F32);

  if (role == 3) {
    // E chain: rv holds E_t^T[y][h]; E_{t+1} = Wx_d @ E_t. 25 stores.
    for (int i = tid; i < 32 * NHD; i += 256)
      rv[0][(i >> 7) * RVS + (i & 127)] = W_out[(i & 127) * NYD + (i >> 7)];
    bf16x8 Af[2][4];
#pragma unroll
    for (int mt = 0; mt < 2; ++mt)
#pragma unroll
      for (int kt = 0; kt < 4; ++kt) {
        const float* pa = W_dec + (size_t)((wave * 2 + mt) * 16 + l16) * NHD + kt * 32 + qs;
        Af[mt][kt] = cvt8(*(const float4*)pa, *(const float4*)(pa + 4));
      }
    __syncthreads();
    int p = 0;
    for (int t = 0; t < 25; ++t) {
      float* Ec = rv[p];
      float* En = rv[p ^ 1];
      for (int i = tid; i < 4096; i += 256)
        ws[WS_EW + t * 4096 + i] = (__bf16)Ec[(i >> 7) * RVS + (i & 127)];
      if (t < 24) {
#pragma unroll
        for (int nt = 0; nt < 2; ++nt) {
          bf16x8 Bf[4];
#pragma unroll
          for (int kt = 0; kt < 4; ++kt) {
            const float* pb = &Ec[(nt * 16 + l16) * RVS + kt * 32 + qs];
            Bf[kt] = cvt8(*(const float4*)pb, *(const float4*)(pb + 4));
          }
#pragma unroll
          for (int mt = 0; mt < 2; ++mt) {
            f32x4 a0 = {0.f, 0.f, 0.f, 0.f}, a1 = {0.f, 0.f, 0.f, 0.f};
            a0 = MFMA16(Af[mt][0], Bf[0], a0);
            a0 = MFMA16(Af[mt][1], Bf[1], a0);
            a1 = MFMA16(Af[mt][2], Bf[2], a1);
            a1 = MFMA16(Af[mt][3], Bf[3], a1);
            a0 += a1;
#pragma unroll
            for (int r = 0; r < 4; ++r)
              En[(nt * 16 + l16) * RVS + (wave * 2 + mt) * 16 + q * 4 + r] = a0[r];
          }
        }
      }
      __syncthreads();
      p ^= 1;
    }
    return;
  }

  // roles 0..2: right-multiply chains on a 48x128 state (row 32 = bias row).
  const float* W0; const float* bias; const float* Wx; int nsteps; __bf16* gout;
  if (role == 0)      { W0 = W_dec + NHD * NHD; bias = b_dec;  Wx = W_dec; nsteps = 25; gout = nullptr; }
  else if (role == 1) { W0 = W_enc + NHD * NHD; bias = b_enc;  Wx = W_enc; nsteps = 24; gout = ws + WS_GY; }
  else                { W0 = W_enc + (NHD + NYD) * NHD; bias = nullptr; Wx = W_enc; nsteps = 24; gout = ws + WS_GU; }

  for (int i = tid; i < 48 * NHD; i += 256) {
    int row = i >> 7, col = i & 127;
    float v = 0.f;
    if (row < 32) v = W0[row * NHD + col];
    else if (row == 32 && bias) v = bias[col];
    rv[0][row * RVS + col] = v;
  }
  bf16x8 Bx[4][2];
#pragma unroll
  for (int kt = 0; kt < 4; ++kt)
#pragma unroll
    for (int nt = 0; nt < 2; ++nt)
      Bx[kt][nt] = gather_w(Wx, NHD, kt * 32 + qs, wave * 32 + nt * 16 + l16);
  bf16x8 Bo[4];
  if (role == 0) {
#pragma unroll
    for (int kt = 0; kt < 4; ++kt)
      Bo[kt] = gather_w(W_out, NYD, kt * 32 + qs, (wave & 1) * 16 + l16);
  }
  f32x4 gacc = {0.f, 0.f, 0.f, 0.f};
  float breg = 0.f;
  __syncthreads();

  int p = 0;
  for (int k = 0; k < nsteps; ++k) {
    if (role == 0) {
      if (wave < 2 && q == 0) {  // gamma_k = b_out + sum_{j<k} bv_j @ W_out
        float gv = gacc[0] + b_out[wave * 16 + l16];
        if (k < 24) Fz[k * 32 + wave * 16 + l16] = gv;
        else
          for (int t = 24; t <= 33; ++t)  // gamma_24..32 + gamma_inf(33)
            Fz[t * 32 + wave * 16 + l16] = gv;
      }
    } else {
      for (int i = tid; i < 4096; i += 256) {  // conflict-free read, [k][h][y] store
        int y = i >> 7, h = i & 127;
        gout[k * 4096 + h * 32 + y] = (__bf16)rv[p][y * RVS + h];
      }
      if (bias && tid < 128) breg += rv[p][32 * RVS + tid];  // beta partial
    }
    if (k + 1 < nsteps) {  // final state update is dead -> skip
#pragma unroll
      for (int Mt = 0; Mt < 3; ++Mt) {
        bf16x8 A[4];
#pragma unroll
        for (int kt = 0; kt < 4; ++kt) {
          const float* pa = &rv[p][(Mt * 16 + l16) * RVS + kt * 32 + qs];
          A[kt] = cvt8(*(const float4*)pa, *(const float4*)(pa + 4));
        }
        f32x4 a0 = {0.f, 0.f, 0.f, 0.f}, a1 = {0.f, 0.f, 0.f, 0.f};
#pragma unroll
        for (int kt = 0; kt < 4; ++kt) {
          a0 = MFMA16(A[kt], Bx[kt][0], a0);
          a1 = MFMA16(A[kt], Bx[kt][1], a1);
        }
#pragma unroll
        for (int r = 0; r < 4; ++r) {
          rv[p ^ 1][(Mt * 16 + q * 4 + r) * RVS + wave * 32 + l16]      = a0[r];
          rv[p ^ 1][(Mt * 16 + q * 4 + r) * RVS + wave * 32 + 16 + l16] = a1[r];
        }
        if (role == 0 && wave < 2) {
          if (Mt < 2 && k < KTAP) {  // R_k store
            f32x4 ar = {0.f, 0.f, 0.f, 0.f};
#pragma unroll
            for (int kt = 0; kt < 4; ++kt) ar = MFMA16(A[kt], Bo[kt], ar);
            bf16x4 hh;
#pragma unroll
            for (int r = 0; r < 4; ++r) hh[r] = (__bf16)ar[r];
            *(bf16x4*)(ws + WS_RK + k * 1024 + (wave * 16 + l16) * 32 + Mt * 16 + q * 4) = hh;
          } else if (Mt == 2) {  // bias row @ W_out into gacc
#pragma unroll
            for (int kt = 0; kt < 4; ++kt) gacc = MFMA16(A[kt], Bo[kt], gacc);
          }
        }
      }
    }
    __syncthreads();
    p ^= 1;
  }
  if (role == 1 && tid < 128) Fz[34 * 32 + tid] = breg;
}

// ============================ main kernel ============================
__global__ __launch_bounds__(512, 4) void fused_rnn(
    const float* __restrict__ Y0, const float* __restrict__ U0,
    const float* __restrict__ U1, const __bf16* __restrict__ ws,
    float* __restrict__ out) {
  __shared__ __align__(16) __bf16 ubc[55 * 512];  // 56320 B -> 2 WG/CU

  const int tid  = threadIdx.x;
  const int wave = tid >> 6;
  const int lane = tid & 63;
  const int q    = lane >> 4;
  const int l16  = lane & 15;
  const int qs   = q * 8;
  const int chunk = blockIdx.x & (NCH - 1);
  const int b0    = (blockIdx.x >> 4) * MB;

  const __bf16* Rk = ws + WS_RK;
  const float*  Fz = (const float*)(ws + WS_F32);

  if (chunk == 0) {
    // =================== head: rows 0..32, fully parallel ===================
    // phase A: x_enc in registers (global Y0/U0 + Gy/Gu, no scan)
    const __bf16* Gyp = ws + WS_GY + (wave * 16 + l16) * 32 + qs;
    const __bf16* Gup = ws + WS_GU + (wave * 16 + l16) * 32 + qs;
    f32x4 ax0 = {0.f, 0.f, 0.f, 0.f}, ax1 = {0.f, 0.f, 0.f, 0.f};
#pragma unroll 4
    for (int k = 0; k < TENC; ++k) {
      const float* py = Y0 + ((size_t)(TSEQ - 1 - k) * NBAT + b0 + l16) * NYD + qs;
      const float* pu = U0 + ((size_t)(TSEQ - 1 - k) * NBAT + b0 + l16) * NUD + qs;
      bf16x8 Ya = cvt8(*(const float4*)py, *(const float4*)(py + 4));
      bf16x8 Ua = cvt8(*(const float4*)pu, *(const float4*)(pu + 4));
      ax0 = MFMA16(Ya, *(const bf16x8*)(Gyp + k * 4096), ax0);
      ax1 = MFMA16(Ua, *(const bf16x8*)(Gup + k * 4096), ax1);
    }
    ax0 += ax1;
    // phase B: x_enc frags -> first 4 KiB of ubc (zero-slot region)
    {
      float bcol = Fz[34 * 32 + wave * 16 + l16];
      int h = wave * 16 + l16, hc = h >> 3, hl = h & 7;
#pragma unroll
      for (int r = 0; r < 4; ++r)
        ubc[(hc * 16 + q * 4 + r) * 8 + hl] = (__bf16)(ax0[r] + bcol);
    }
    __syncthreads();
    // phase C: all waves pick up x_enc A-frags
    bf16x8 xa_e[4];
#pragma unroll
    for (int kt = 0; kt < 4; ++kt)
      xa_e[kt] = *(const bf16x8*)(ubc + ((kt * 4 + q) * 16 + l16) * 8);
    __syncthreads();
    // phase D: stage window. slot s <-> u1 row s-23: 0..22 zero, 23..54 real.
    for (int i = tid; i < 55 * 64; i += 512) {
      int t = i >> 6, slot = i & 63, b = slot & 15, u8 = (slot >> 4) * 8;
      bf16x8 v;
#pragma unroll
      for (int j = 0; j < 8; ++j) v[j] = (__bf16)0.f;
      if (t >= 23) {
        const float* ps = U1 + ((size_t)(t - 23) * NBAT + b0 + b) * NUD + u8;
        v = cvt8(*(const float4*)ps, *(const float4*)(ps + 4));
      }
      *(bf16x8*)(ubc + i * 8) = v;
    }
    __syncthreads();

    // phase E: E-term + conv + stores
    const int t0r = 1 + wave * 4;  // this wave's rows t0r..t0r+3
    f32x4 acc[4][2];
#pragma unroll
    for (int r = 0; r < 4; ++r) {
      acc[r][0] = (f32x4){0.f, 0.f, 0.f, 0.f};
      acc[r][1] = (f32x4){0.f, 0.f, 0.f, 0.f};
    }
#define EWF(t, nt, kt) (*(const bf16x8*)(ws + WS_EW + (t) * 4096 + ((nt) * 16 + l16) * 128 + (kt) * 32 + qs))
    if (wave < 6) {  // E-term only for t <= 24 (||Wx^25|| ~ 1e-6)
#pragma unroll
      for (int r = 0; r < 4; ++r) {
        int t = t0r + r;
#pragma unroll
        for (int kt = 0; kt < 4; ++kt) {
          acc[r][0] = MFMA16(EWF(t, 0, kt), xa_e[kt], acc[r][0]);
          acc[r][1] = MFMA16(EWF(t, 1, kt), xa_e[kt], acc[r][1]);
        }
      }
    }
    f32x4 e0a = {0.f, 0.f, 0.f, 0.f}, e0b = {0.f, 0.f, 0.f, 0.f};
    if (wave == 7) {  // row 0 = x_enc@W_out + gamma_0 (no conv term)
#pragma unroll
      for (int kt = 0; kt < 4; ++kt) {
        e0a = MFMA16(EWF(0, 0, kt), xa_e[kt], e0a);
        e0b = MFMA16(EWF(0, 1, kt), xa_e[kt], e0b);
      }
    }
#undef EWF

    conv24ring(Rk, ubc + (t0r - 1) * 512, l16, qs, lane, acc);

#pragma unroll
    for (int r = 0; r < 4; ++r) {
      int t = t0r + r;
      f32x4 g0 = *(const f32x4*)(Fz + t * 32 + q * 4);
      f32x4 g1 = *(const f32x4*)(Fz + t * 32 + 16 + q * 4);
      float* po = out + ((size_t)t * NBAT + b0 + l16) * NYD + q * 4;
      *(f32x4*)po        = acc[r][0] + g0;
      *(f32x4*)(po + 16) = acc[r][1] + g1;
    }
    if (wave == 7) {
      f32x4 g0 = *(const f32x4*)(Fz + q * 4);
      f32x4 g1 = *(const f32x4*)(Fz + 16 + q * 4);
      float* po = out + ((size_t)(b0 + l16)) * NYD + q * 4;
      *(f32x4*)po        = e0a + g0;
      *(f32x4*)(po + 16) = e0b + g1;
    }

  } else {
    // ===== std conv: rows g0..g0+31, g0 = 32*chunk+1 (chunks 1..15) =====
    const int g0  = chunk * LCH + 1;
    const int tw0 = g0 - KTAP;  // >= 9, all slots real
    for (int i = tid; i < 55 * 64; i += 512) {
      int t = i >> 6, slot = i & 63, b = slot & 15, u8 = (slot >> 4) * 8;
      const float* ps = U1 + ((size_t)(tw0 + t) * NBAT + b0 + b) * NUD + u8;
      float4 a = *(const float4*)ps;
      float4 c = *(const float4*)(ps + 4);
      *(bf16x8*)(ubc + i * 8) = cvt8(a, c);
    }
    f32x4 gv0 = *(const f32x4*)(Fz + 33 * 32 + q * 4);
    f32x4 gv1 = *(const f32x4*)(Fz + 33 * 32 + 16 + q * 4);
    __syncthreads();

    f32x4 acc[4][2];
#pragma unroll
    for (int r = 0; r < 4; ++r) {
      acc[r][0] = (f32x4){0.f, 0.f, 0.f, 0.f};
      acc[r][1] = (f32x4){0.f, 0.f, 0.f, 0.f};
    }
    conv24ring(Rk, ubc + wave * 4 * 512, l16, qs, lane, acc);

    const int gw0 = g0 + wave * 4;
#pragma unroll
    for (int r = 0; r < 4; ++r) {
      float* po = out + ((size_t)(gw0 + r) * NBAT + b0 + l16) * NYD + q * 4;
      *(f32x4*)po        = acc[r][0] + gv0;
      *(f32x4*)(po + 16) = acc[r][1] + gv1;
    }
  }
}

extern "C" void kernel_launch(void* const* d_in, const int* in_sizes, int n_in,
                              void* d_out, int out_size, void* d_ws, size_t ws_size,
                              hipStream_t stream) {
  const float* Y0    = (const float*)d_in[0];
  const float* U0    = (const float*)d_in[1];
  const float* U1    = (const float*)d_in[2];
  const float* W_enc = (const float*)d_in[3];
  const float* b_enc = (const float*)d_in[4];
  const float* W_dec = (const float*)d_in[5];
  const float* b_dec = (const float*)d_in[6];
  const float* W_out = (const float*)d_in[7];
  const float* b_out = (const float*)d_in[8];
  float* out = (float*)d_out;
  (void)in_sizes; (void)n_in; (void)out_size; (void)ws_size;
  __bf16* tws = (__bf16*)d_ws;  // ~652 KiB: Rk/Gy/Gu/E bf16 + gamma/beta f32
  hipLaunchKernelGGL(make_tabs, dim3(4), dim3(256), 0, stream,
                     W_enc, b_enc, W_dec, b_dec, W_out, b_out, tws);
  hipLaunchKernelGGL(fused_rnn, dim3(NCH * (NBAT / MB)), dim3(512), 0, stream,
                     Y0, U0, U1, (const __bf16*)tws, out);
}

// Round 4
// 323.954 us; speedup vs baseline: 1.2536x; 1.2536x over previous
//
#include <hip/hip_runtime.h>

// Fused truncated-scan linear RNN for MI355X (gfx950) — round 6.
//
// vs round 5: occupancy forensics — 15% occupancy with 8-wave WGs means
// ~1 WG/CU resident: the 56KB/512-thread WG shape left ~1 wave/SIMD (no
// TLP to hide global tap-load latency) and 4 serial dispatch rounds.
// This round quarters the WG (256 thr, 16 output rows, 39KB window ->
// 4 WG/CU by LDS) and doubles the grid (2048 WGs, 2 rounds). Per-wave
// math is UNCHANGED (same verified conv24ring, 192 MFMAs/wave). Tap
// pipeline deepened to 3 iterations. bid = chunk*64+btile pins all
// chunks of a btile to one XCD and co-schedules adjacent chunks ->
// window-halo L2 reuse. Head (x_enc / E-term / row 0) refactored onto
// chunks 0-1 with identical math; make_tabs unchanged.

#define TSEQ 512
#define NBAT 1024
#define NYD  32
#define NUD  32
#define NHD  128
#define MB   16    // batch rows per workgroup (one MFMA M-tile)
#define LCH  16    // output rows per chunk
#define NCHK 32    // chunks (0,1 = head rows 1..32 + row 0; 2..31 conv)
#define TENC 24    // encoder taps (truncated history)
#define KTAP 24    // decoder conv taps == truncation depth
#define WROWS 39   // staged window rows: 23 halo + 16
#define RVS  132   // precompute LDS row stride (f32)

typedef __bf16 bf16x8 __attribute__((ext_vector_type(8)));
typedef __bf16 bf16x4 __attribute__((ext_vector_type(4)));
typedef float  f32x4  __attribute__((ext_vector_type(4)));

#define MFMA16(a, b, c) __builtin_amdgcn_mfma_f32_16x16x32_bf16((a), (b), (c), 0, 0, 0)

// workspace layout (bf16 element offsets)
#define WS_RK  0                       // [24][32][32]  R_k (value R_k[u][n] at [k][n][u])
#define WS_GY  (24 * 1024)             // [24][128][32] Gy_k^T (value Gy_k[y][h] at [k][h][y])
#define WS_GU  (WS_GY + 24 * 4096)     // [24][128][32] Gu_k^T
#define WS_EW  (WS_GU + 24 * 4096)     // [25][32][128] E_t^T  (value E_t[h][y] at [t][y][h])
#define WS_F32 (WS_EW + 25 * 4096)     // f32: gamma[34][32] (33=inf), beta[128]

__device__ __forceinline__ bf16x8 gather_w(const float* __restrict__ W, int ld,
                                           int k0, int col) {
  bf16x8 r;
#pragma unroll
  for (int j = 0; j < 8; ++j) r[j] = (__bf16)W[(k0 + j) * ld + col];
  return r;
}

__device__ __forceinline__ bf16x8 cvt8(float4 a, float4 b) {
  bf16x8 r;
  r[0] = (__bf16)a.x; r[1] = (__bf16)a.y; r[2] = (__bf16)a.z; r[3] = (__bf16)a.w;
  r[4] = (__bf16)b.x; r[5] = (__bf16)b.y; r[6] = (__bf16)b.z; r[7] = (__bf16)b.w;
  return r;
}

// 24-tap conv, 4-deep LDS window ring + 3-deep global tap pipeline.
__device__ __forceinline__ void conv24ring(const __bf16* __restrict__ taps,
                                           const __bf16* __restrict__ ub,
                                           int l16, int qs, int lane,
                                           f32x4 acc[4][2]) {
#define TAPF(k, mt) (*(const bf16x8*)(taps + (k) * 1024 + ((mt) * 16 + l16) * 32 + qs))
#define WINF(i)     (*(const bf16x8*)(ub + (i) * 512 + lane * 8))
  bf16x8 w[4];
  w[23 & 3] = WINF(23);
  w[24 & 3] = WINF(24);
  w[25 & 3] = WINF(25);
  w[26 & 3] = WINF(26);
  bf16x8 t0a = TAPF(0, 0), t0b = TAPF(0, 1);
  bf16x8 t1a = TAPF(1, 0), t1b = TAPF(1, 1);
  bf16x8 t2a = TAPF(2, 0), t2b = TAPF(2, 1);
#pragma unroll
  for (int k = 0; k < KTAP; ++k) {
    bf16x8 t3a, t3b, wn;
    if (k + 3 < KTAP) { t3a = TAPF(k + 3, 0); t3b = TAPF(k + 3, 1); }
    if (k + 1 < KTAP) wn = WINF(22 - k);
#pragma unroll
    for (int r = 0; r < 4; ++r) {
      acc[r][0] = MFMA16(t0a, w[(23 - k + r) & 3], acc[r][0]);
      acc[r][1] = MFMA16(t0b, w[(23 - k + r) & 3], acc[r][1]);
    }
    if (k + 1 < KTAP) w[(22 - k) & 3] = wn;
    t0a = t1a; t0b = t1b; t1a = t2a; t1b = t2b;
    if (k + 3 < KTAP) { t2a = t3a; t2b = t3b; }
  }
#undef TAPF
#undef WINF
}

// ============ precompute: 4 parallel WGs, one per serial chain ============
__global__ __launch_bounds__(256) void make_tabs(
    const float* __restrict__ W_enc, const float* __restrict__ b_enc,
    const float* __restrict__ W_dec, const float* __restrict__ b_dec,
    const float* __restrict__ W_out, const float* __restrict__ b_out,
    __bf16* __restrict__ ws) {
  __shared__ __align__(16) float rv[2][48 * RVS];
  const int tid = threadIdx.x;
  const int wave = tid >> 6, lane = tid & 63;
  const int q = lane >> 4, l16 = lane & 15, qs = q * 8;
  const int role = blockIdx.x;
  float* Fz = (float*)(ws + WS_F32);

  if (role == 3) {
    // E chain: rv holds E_t^T[y][h]; E_{t+1} = Wx_d @ E_t. 25 stores.
    for (int i = tid; i < 32 * NHD; i += 256)
      rv[0][(i >> 7) * RVS + (i & 127)] = W_out[(i & 127) * NYD + (i >> 7)];
    bf16x8 Af[2][4];
#pragma unroll
    for (int mt = 0; mt < 2; ++mt)
#pragma unroll
      for (int kt = 0; kt < 4; ++kt) {
        const float* pa = W_dec + (size_t)((wave * 2 + mt) * 16 + l16) * NHD + kt * 32 + qs;
        Af[mt][kt] = cvt8(*(const float4*)pa, *(const float4*)(pa + 4));
      }
    __syncthreads();
    int p = 0;
    for (int t = 0; t < 25; ++t) {
      float* Ec = rv[p];
      float* En = rv[p ^ 1];
      for (int i = tid; i < 4096; i += 256)
        ws[WS_EW + t * 4096 + i] = (__bf16)Ec[(i >> 7) * RVS + (i & 127)];
      if (t < 24) {
#pragma unroll
        for (int nt = 0; nt < 2; ++nt) {
          bf16x8 Bf[4];
#pragma unroll
          for (int kt = 0; kt < 4; ++kt) {
            const float* pb = &Ec[(nt * 16 + l16) * RVS + kt * 32 + qs];
            Bf[kt] = cvt8(*(const float4*)pb, *(const float4*)(pb + 4));
          }
#pragma unroll
          for (int mt = 0; mt < 2; ++mt) {
            f32x4 a0 = {0.f, 0.f, 0.f, 0.f}, a1 = {0.f, 0.f, 0.f, 0.f};
            a0 = MFMA16(Af[mt][0], Bf[0], a0);
            a0 = MFMA16(Af[mt][1], Bf[1], a0);
            a1 = MFMA16(Af[mt][2], Bf[2], a1);
            a1 = MFMA16(Af[mt][3], Bf[3], a1);
            a0 += a1;
#pragma unroll
            for (int r = 0; r < 4; ++r)
              En[(nt * 16 + l16) * RVS + (wave * 2 + mt) * 16 + q * 4 + r] = a0[r];
          }
        }
      }
      __syncthreads();
      p ^= 1;
    }
    return;
  }

  // roles 0..2: right-multiply chains on a 48x128 state (row 32 = bias row).
  const float* W0; const float* bias; const float* Wx; int nsteps; __bf16* gout;
  if (role == 0)      { W0 = W_dec + NHD * NHD; bias = b_dec;  Wx = W_dec; nsteps = 25; gout = nullptr; }
  else if (role == 1) { W0 = W_enc + NHD * NHD; bias = b_enc;  Wx = W_enc; nsteps = 24; gout = ws + WS_GY; }
  else                { W0 = W_enc + (NHD + NYD) * NHD; bias = nullptr; Wx = W_enc; nsteps = 24; gout = ws + WS_GU; }

  for (int i = tid; i < 48 * NHD; i += 256) {
    int row = i >> 7, col = i & 127;
    float v = 0.f;
    if (row < 32) v = W0[row * NHD + col];
    else if (row == 32 && bias) v = bias[col];
    rv[0][row * RVS + col] = v;
  }
  bf16x8 Bx[4][2];
#pragma unroll
  for (int kt = 0; kt < 4; ++kt)
#pragma unroll
    for (int nt = 0; nt < 2; ++nt)
      Bx[kt][nt] = gather_w(Wx, NHD, kt * 32 + qs, wave * 32 + nt * 16 + l16);
  bf16x8 Bo[4];
  if (role == 0) {
#pragma unroll
    for (int kt = 0; kt < 4; ++kt)
      Bo[kt] = gather_w(W_out, NYD, kt * 32 + qs, (wave & 1) * 16 + l16);
  }
  f32x4 gacc = {0.f, 0.f, 0.f, 0.f};
  float breg = 0.f;
  __syncthreads();

  int p = 0;
  for (int k = 0; k < nsteps; ++k) {
    if (role == 0) {
      if (wave < 2 && q == 0) {  // gamma_k = b_out + sum_{j<k} bv_j @ W_out
        float gv = gacc[0] + b_out[wave * 16 + l16];
        if (k < 24) Fz[k * 32 + wave * 16 + l16] = gv;
        else
          for (int t = 24; t <= 33; ++t)  // gamma_24..32 + gamma_inf(33)
            Fz[t * 32 + wave * 16 + l16] = gv;
      }
    } else {
      for (int i = tid; i < 4096; i += 256) {  // conflict-free read, [k][h][y] store
        int y = i >> 7, h = i & 127;
        gout[k * 4096 + h * 32 + y] = (__bf16)rv[p][y * RVS + h];
      }
      if (bias && tid < 128) breg += rv[p][32 * RVS + tid];  // beta partial
    }
    if (k + 1 < nsteps) {  // final state update is dead -> skip
#pragma unroll
      for (int Mt = 0; Mt < 3; ++Mt) {
        bf16x8 A[4];
#pragma unroll
        for (int kt = 0; kt < 4; ++kt) {
          const float* pa = &rv[p][(Mt * 16 + l16) * RVS + kt * 32 + qs];
          A[kt] = cvt8(*(const float4*)pa, *(const float4*)(pa + 4));
        }
        f32x4 a0 = {0.f, 0.f, 0.f, 0.f}, a1 = {0.f, 0.f, 0.f, 0.f};
#pragma unroll
        for (int kt = 0; kt < 4; ++kt) {
          a0 = MFMA16(A[kt], Bx[kt][0], a0);
          a1 = MFMA16(A[kt], Bx[kt][1], a1);
        }
#pragma unroll
        for (int r = 0; r < 4; ++r) {
          rv[p ^ 1][(Mt * 16 + q * 4 + r) * RVS + wave * 32 + l16]      = a0[r];
          rv[p ^ 1][(Mt * 16 + q * 4 + r) * RVS + wave * 32 + 16 + l16] = a1[r];
        }
        if (role == 0 && wave < 2) {
          if (Mt < 2 && k < KTAP) {  // R_k store
            f32x4 ar = {0.f, 0.f, 0.f, 0.f};
#pragma unroll
            for (int kt = 0; kt < 4; ++kt) ar = MFMA16(A[kt], Bo[kt], ar);
            bf16x4 hh;
#pragma unroll
            for (int r = 0; r < 4; ++r) hh[r] = (__bf16)ar[r];
            *(bf16x4*)(ws + WS_RK + k * 1024 + (wave * 16 + l16) * 32 + Mt * 16 + q * 4) = hh;
          } else if (Mt == 2) {  // bias row @ W_out into gacc
#pragma unroll
            for (int kt = 0; kt < 4; ++kt) gacc = MFMA16(A[kt], Bo[kt], gacc);
          }
        }
      }
    }
    __syncthreads();
    p ^= 1;
  }
  if (role == 1 && tid < 128) Fz[34 * 32 + tid] = breg;
}

// ============================ main kernel ============================
__global__ __launch_bounds__(256, 4) void fused_rnn(
    const float* __restrict__ Y0, const float* __restrict__ U0,
    const float* __restrict__ U1, const __bf16* __restrict__ ws,
    float* __restrict__ out) {
  __shared__ __align__(16) __bf16 ubc[WROWS * 512];  // 39936 B -> 4 WG/CU

  const int tid  = threadIdx.x;
  const int wave = tid >> 6;   // 0..3
  const int lane = tid & 63;
  const int q    = lane >> 4;
  const int l16  = lane & 15;
  const int qs   = q * 8;
  const int chunk = blockIdx.x >> 6;        // 0..31
  const int b0    = (blockIdx.x & 63) * MB; // bid%8 = btile%8 -> XCD-pinned
  const bool head = (chunk < 2);

  const __bf16* Rk = ws + WS_RK;
  const float*  Fz = (const float*)(ws + WS_F32);

  const int g0  = chunk * LCH + 1;   // rows g0..g0+15
  const int tw0 = g0 - 24;           // window slot s <-> u1 row tw0+s
  const int t0r = g0 + wave * 4;     // this wave's 4 output rows

  bf16x8 xa_e[4];
  if (head) {
    // phase A: x_enc (h-cols wave*32..+31) via Gy/Gu conv — no scan.
    f32x4 ax0 = {0.f, 0.f, 0.f, 0.f}, bx0 = {0.f, 0.f, 0.f, 0.f};
    f32x4 ax1 = {0.f, 0.f, 0.f, 0.f}, bx1 = {0.f, 0.f, 0.f, 0.f};
    const __bf16* Gy0 = ws + WS_GY + (wave * 32 + l16) * 32 + qs;
    const __bf16* Gy1 = ws + WS_GY + (wave * 32 + 16 + l16) * 32 + qs;
    const __bf16* Gu0 = ws + WS_GU + (wave * 32 + l16) * 32 + qs;
    const __bf16* Gu1 = ws + WS_GU + (wave * 32 + 16 + l16) * 32 + qs;
#pragma unroll 4
    for (int k = 0; k < TENC; ++k) {
      const float* py = Y0 + ((size_t)(TSEQ - 1 - k) * NBAT + b0 + l16) * NYD + qs;
      const float* pu = U0 + ((size_t)(TSEQ - 1 - k) * NBAT + b0 + l16) * NUD + qs;
      bf16x8 Ya = cvt8(*(const float4*)py, *(const float4*)(py + 4));
      bf16x8 Ua = cvt8(*(const float4*)pu, *(const float4*)(pu + 4));
      ax0 = MFMA16(Ya, *(const bf16x8*)(Gy0 + k * 4096), ax0);
      bx0 = MFMA16(Ua, *(const bf16x8*)(Gu0 + k * 4096), bx0);
      ax1 = MFMA16(Ya, *(const bf16x8*)(Gy1 + k * 4096), ax1);
      bx1 = MFMA16(Ua, *(const bf16x8*)(Gu1 + k * 4096), bx1);
    }
    ax0 += bx0; ax1 += bx1;
    // phase B: x_enc frags -> ubc slots 0..3 (zero-halo region)
#pragma unroll
    for (int nt = 0; nt < 2; ++nt) {
      int h = wave * 32 + nt * 16 + l16;
      float bcol = Fz[34 * 32 + h];
      int hc = h >> 3, hl = h & 7;
      f32x4 av = nt ? ax1 : ax0;
#pragma unroll
      for (int r = 0; r < 4; ++r)
        ubc[(hc * 16 + q * 4 + r) * 8 + hl] = (__bf16)(av[r] + bcol);
    }
    __syncthreads();
#pragma unroll
    for (int kt = 0; kt < 4; ++kt)
      xa_e[kt] = *(const bf16x8*)(ubc + ((kt * 4 + q) * 16 + l16) * 8);
    __syncthreads();
  }

  // stage window: slot s <-> u1 row tw0+s; rows < 0 are zeros (head only).
  for (int i = tid; i < WROWS * 64; i += 256) {
    int s = i >> 6, slot = i & 63, b = slot & 15, u8 = (slot >> 4) * 8;
    int t = tw0 + s;
    bf16x8 v;
#pragma unroll
    for (int j = 0; j < 8; ++j) v[j] = (__bf16)0.f;
    if (t >= 0) {
      const float* ps = U1 + ((size_t)t * NBAT + b0 + b) * NUD + u8;
      v = cvt8(*(const float4*)ps, *(const float4*)(ps + 4));
    }
    *(bf16x8*)(ubc + i * 8) = v;
  }
  __syncthreads();

  f32x4 acc[4][2];
#pragma unroll
  for (int r = 0; r < 4; ++r) {
    acc[r][0] = (f32x4){0.f, 0.f, 0.f, 0.f};
    acc[r][1] = (f32x4){0.f, 0.f, 0.f, 0.f};
  }

  f32x4 e0a = {0.f, 0.f, 0.f, 0.f}, e0b = {0.f, 0.f, 0.f, 0.f};
  if (head) {
#define EWF(t, nt, kt) (*(const bf16x8*)(ws + WS_EW + (t) * 4096 + ((nt) * 16 + l16) * 128 + (kt) * 32 + qs))
    if (t0r <= 21) {  // E-term for rows t <= 24 (||Wx^25|| ~ 1e-6)
#pragma unroll
      for (int r = 0; r < 4; ++r) {
        int t = t0r + r;
#pragma unroll
        for (int kt = 0; kt < 4; ++kt) {
          acc[r][0] = MFMA16(EWF(t, 0, kt), xa_e[kt], acc[r][0]);
          acc[r][1] = MFMA16(EWF(t, 1, kt), xa_e[kt], acc[r][1]);
        }
      }
    }
    if (chunk == 0 && wave == 0) {  // row 0 = x_enc@W_out + gamma_0
#pragma unroll
      for (int kt = 0; kt < 4; ++kt) {
        e0a = MFMA16(EWF(0, 0, kt), xa_e[kt], e0a);
        e0b = MFMA16(EWF(0, 1, kt), xa_e[kt], e0b);
      }
    }
#undef EWF
  }

  conv24ring(Rk, ubc + wave * 4 * 512, l16, qs, lane, acc);

  if (head) {  // per-row gamma
#pragma unroll
    for (int r = 0; r < 4; ++r) {
      int t = t0r + r;
      f32x4 g0v = *(const f32x4*)(Fz + t * 32 + q * 4);
      f32x4 g1v = *(const f32x4*)(Fz + t * 32 + 16 + q * 4);
      float* po = out + ((size_t)t * NBAT + b0 + l16) * NYD + q * 4;
      *(f32x4*)po        = acc[r][0] + g0v;
      *(f32x4*)(po + 16) = acc[r][1] + g1v;
    }
    if (chunk == 0 && wave == 0) {
      f32x4 g0v = *(const f32x4*)(Fz + q * 4);
      f32x4 g1v = *(const f32x4*)(Fz + 16 + q * 4);
      float* po = out + ((size_t)(b0 + l16)) * NYD + q * 4;
      *(f32x4*)po        = e0a + g0v;
      *(f32x4*)(po + 16) = e0b + g1v;
    }
  } else {  // gamma_inf
    f32x4 gv0 = *(const f32x4*)(Fz + 33 * 32 + q * 4);
    f32x4 gv1 = *(const f32x4*)(Fz + 33 * 32 + 16 + q * 4);
#pragma unroll
    for (int r = 0; r < 4; ++r) {
      float* po = out + ((size_t)(t0r + r) * NBAT + b0 + l16) * NYD + q * 4;
      *(f32x4*)po        = acc[r][0] + gv0;
      *(f32x4*)(po + 16) = acc[r][1] + gv1;
    }
  }
}

extern "C" void kernel_launch(void* const* d_in, const int* in_sizes, int n_in,
                              void* d_out, int out_size, void* d_ws, size_t ws_size,
                              hipStream_t stream) {
  const float* Y0    = (const float*)d_in[0];
  const float* U0    = (const float*)d_in[1];
  const float* U1    = (const float*)d_in[2];
  const float* W_enc = (const float*)d_in[3];
  const float* b_enc = (const float*)d_in[4];
  const float* W_dec = (const float*)d_in[5];
  const float* b_dec = (const float*)d_in[6];
  const float* W_out = (const float*)d_in[7];
  const float* b_out = (const float*)d_in[8];
  float* out = (float*)d_out;
  (void)in_sizes; (void)n_in; (void)out_size; (void)ws_size;
  __bf16* tws = (__bf16*)d_ws;  // ~652 KiB: Rk/Gy/Gu/E bf16 + gamma/beta f32
  hipLaunchKernelGGL(make_tabs, dim3(4), dim3(256), 0, stream,
                     W_enc, b_enc, W_dec, b_dec, W_out, b_out, tws);
  hipLaunchKernelGGL(fused_rnn, dim3(NCHK * (NBAT / MB)), dim3(256), 0, stream,
                     Y0, U0, U1, (const __bf16*)tws, out);
}